// Round 5
// baseline (2376.194 us; speedup 1.0000x reference)
//
#include <hip/hip_runtime.h>
#include <hip/hip_bf16.h>

#define BB 512
#define SS 2048
#define VV 29
#define HH 128

__device__ __forceinline__ float fast_tanh(float z) {
    // tanh(z) = sign(z) * (1 - 2e/(1+e)),  e = exp(-2|z|)
    float az = fabsf(z);
    float e  = __expf(-2.0f * az);
    float r  = 1.0f - 2.0f * e * __builtin_amdgcn_rcpf(1.0f + e);
    return copysignf(r, z);
}

// One block per batch row, 128 threads = 2 waves. Thread i owns output i with
// the FULL K=128 dot (weights in 128 VGPRs). Rationale (round-3/4 calibration):
// the binding resource is per-CU LDS broadcast-read ISSUE count, not barriers.
//   round 2: 248 LDS instrs/CU-step (4 waves x (16 b128 + 15 b32) x 2 blk)
//   round 4: same count but dual-address broadcasts = 2x pipe slots -> slower.
//   this:    ~168 (2 waves x (32+8) b128 x 2 blk), all single-address, and
//            zero redundant tanh / split-K shuffle work. One barrier, 2 waves.
// x prefetch distance-2 via xA/xB ping-pong (period matches unroll-2 => no
// register rotation, vmcnt wait lands ~2 full steps after issue).
// Decoder: single wave, h in lanes, __shfl broadcast, zero barriers, plus
// fixed-point shortcut (dec_in constant => h <- tanh(c+Wh) converges; after
// |dh|<1e-6 across lanes, bulk-fill remaining rows with coalesced dwordx4).
__global__ __launch_bounds__(128, 1) void rnn_fused(
    const float* __restrict__ x,      // (B,S,V)
    const float* __restrict__ We_ih,  // (H,V)
    const float* __restrict__ We_hh,  // (H,H)
    const float* __restrict__ be_ih,  // (H)
    const float* __restrict__ be_hh,  // (H)
    const float* __restrict__ Wd_ih,  // (V,H)
    const float* __restrict__ Wd_hh,  // (V,V)
    const float* __restrict__ bd_ih,  // (V)
    const float* __restrict__ bd_hh,  // (V)
    float* __restrict__ out)          // (B,S,V)
{
    const int b   = blockIdx.x;
    const int tid = threadIdx.x;      // 0..127 == output h-index
    const int i   = tid;

    __shared__ float hbuf[2][HH];
    __shared__ float xbuf[2][32];     // slots 29..31 stay 0

    // ---- weights to registers: full row of We_hh (128 floats, float4 loads) ----
    float wh[HH];
    {
        const float4* wrow4 = reinterpret_cast<const float4*>(We_hh + (size_t)i * HH);
        #pragma unroll
        for (int j = 0; j < HH / 4; ++j) {
            float4 v = wrow4[j];
            wh[4 * j + 0] = v.x; wh[4 * j + 1] = v.y;
            wh[4 * j + 2] = v.z; wh[4 * j + 3] = v.w;
        }
    }
    float wx[32];
    #pragma unroll
    for (int j = 0; j < 32; ++j) wx[j] = (j < VV) ? We_ih[i * VV + j] : 0.0f;
    const float bias = be_ih[i] + be_hh[i];

    const float* xb = x + (size_t)b * SS * VV;

    hbuf[0][tid] = 0.0f;              // h0 = 0
    if (tid < 32) {
        xbuf[0][tid] = (tid < VV) ? xb[tid] : 0.0f;
        xbuf[1][tid] = 0.0f;          // pad slots of buf1 (29..31) stay 0
    }

    // x prefetch registers: xA stored at even steps, xB at odd steps.
    // Entering step T (even): xA = x[T+1]; xB = x[T+2].
    float xA = 0.0f, xB = 0.0f;
    if (tid < VV) {
        xA = xb[VV + tid];            // x[1]
        xB = xb[2 * VV + tid];        // x[2]
    }
    __syncthreads();

    // ---- encoder scan, 2x unrolled ping-pong, ONE barrier/step ----
#define ENC_STEP(CUR, NXT, T, XREG)                                        \
    {                                                                      \
        float xnew = 0.0f;                                                 \
        {                                                                  \
            int tn = (T) + 3; if (tn >= SS) tn = SS - 1;                   \
            if (tid < VV) xnew = xb[tn * VV + tid];                        \
        }                                                                  \
        float a0 = bias, a1 = 0.f, a2 = 0.f, a3 = 0.f;                     \
        const float4* hb4 = reinterpret_cast<const float4*>(&hbuf[CUR][0]);\
        _Pragma("unroll")                                                  \
        for (int j = 0; j < HH / 4; ++j) {                                 \
            float4 hv = hb4[j];                                            \
            a0 += wh[4 * j + 0] * hv.x;                                    \
            a1 += wh[4 * j + 1] * hv.y;                                    \
            a2 += wh[4 * j + 2] * hv.z;                                    \
            a3 += wh[4 * j + 3] * hv.w;                                    \
        }                                                                  \
        const float4* xb4 = reinterpret_cast<const float4*>(&xbuf[CUR][0]);\
        _Pragma("unroll")                                                  \
        for (int k = 0; k < 8; ++k) {                                      \
            float4 xv = xb4[k];                                            \
            a0 += wx[4 * k + 0] * xv.x;                                    \
            a1 += wx[4 * k + 1] * xv.y;                                    \
            a2 += wx[4 * k + 2] * xv.z;                                    \
            a3 += wx[4 * k + 3] * xv.w;                                    \
        }                                                                  \
        float hn = fast_tanh((a0 + a1) + (a2 + a3));                       \
        hbuf[NXT][i] = hn;                                                 \
        if (tid < VV) xbuf[NXT][tid] = XREG;  /* = x[(T)+1], loaded 2 steps ago */ \
        XREG = xnew;                          /* stored again at step (T)+2 */     \
        __syncthreads();                                                   \
    }

    for (int t = 0; t < SS; t += 2) {
        ENC_STEP(0, 1, t,     xA)
        ENC_STEP(1, 0, t + 1, xB)
    }
    // encoded vector in hbuf[0][0..127]; all threads past final barrier.

    // ---- decoder: single wave (threads 0..63), no barriers ----
    if (tid >= 64) return;
    const int lane = tid;
    const int r = (lane < VV) ? lane : (VV - 1);   // lanes >=29 mirror row 28

    // dec_in = encoded @ Wd_ih^T + bd_ih + bd_hh
    float di = bd_ih[r] + bd_hh[r];
    {
        const float* wdi = Wd_ih + r * HH;
        float d0 = 0.f, d1 = 0.f, d2 = 0.f, d3 = 0.f;
        #pragma unroll
        for (int j = 0; j < HH; j += 4) {
            d0 += wdi[j + 0] * hbuf[0][j + 0];
            d1 += wdi[j + 1] * hbuf[0][j + 1];
            d2 += wdi[j + 2] * hbuf[0][j + 2];
            d3 += wdi[j + 3] * hbuf[0][j + 3];
        }
        di += (d0 + d1) + (d2 + d3);
    }

    float wd[VV];
    {
        const float* wdr = Wd_hh + r * VV;
        #pragma unroll
        for (int j = 0; j < VV; ++j) wd[j] = wdr[j];
    }

    float hd = 0.0f;
    float* ob = out + (size_t)b * SS * VV;
    int t = 0;
    for (; t < SS; ++t) {
        float a0 = di, a1 = 0.f, a2 = 0.f, a3 = 0.f;
        #pragma unroll
        for (int j = 0; j < VV; j += 4) {
            a0 += wd[j] * __shfl(hd, j, 64);
            if (j + 1 < VV) a1 += wd[j + 1] * __shfl(hd, j + 1, 64);
            if (j + 2 < VV) a2 += wd[j + 2] * __shfl(hd, j + 2, 64);
            if (j + 3 < VV) a3 += wd[j + 3] * __shfl(hd, j + 3, 64);
        }
        float hn = fast_tanh((a0 + a1) + (a2 + a3));
        int conv = (fabsf(hn - hd) < 1e-6f) ? 1 : 0;
        hd = hn;
        if (lane < VV) ob[(size_t)t * VV + lane] = hn;
        if (__all(conv)) { ++t; break; }
    }

    // ---- fixed-point bulk fill for remaining steps ----
    if (t < SS) {
        // advance t to a multiple of 4 so flat offset t*29 is 16B-aligned
        while (t & 3) {
            if (lane < VV) ob[(size_t)t * VV + lane] = hd;
            ++t;
        }
        if (t < SS) {
            // 58 lanes x float4 = 232 floats/sweep; 232 % 29 == 0 and
            // 232 % 4 == 0 -> constant per-lane phase, exact tiling, no tail.
            const int phi = (4 * lane) % VV;
            float4 v4;
            v4.x = __shfl(hd, phi, 64);
            v4.y = __shfl(hd, (phi + 1) % VV, 64);
            v4.z = __shfl(hd, (phi + 2) % VV, 64);
            v4.w = __shfl(hd, (phi + 3) % VV, 64);
            if (lane < 58) {
                const long fend = (long)SS * VV;
                for (long f = (long)t * VV + 4 * lane; f + 4 <= fend; f += 232) {
                    *reinterpret_cast<float4*>(ob + f) = v4;
                }
            }
        }
    }
}

extern "C" void kernel_launch(void* const* d_in, const int* in_sizes, int n_in,
                              void* d_out, int out_size, void* d_ws, size_t ws_size,
                              hipStream_t stream) {
    const float* x     = (const float*)d_in[0];
    const float* We_ih = (const float*)d_in[1];
    const float* We_hh = (const float*)d_in[2];
    const float* be_ih = (const float*)d_in[3];
    const float* be_hh = (const float*)d_in[4];
    const float* Wd_ih = (const float*)d_in[5];
    const float* Wd_hh = (const float*)d_in[6];
    const float* bd_ih = (const float*)d_in[7];
    const float* bd_hh = (const float*)d_in[8];
    float* out = (float*)d_out;

    rnn_fused<<<dim3(BB), dim3(128), 0, stream>>>(
        x, We_ih, We_hh, be_ih, be_hh, Wd_ih, Wd_hh, bd_ih, bd_hh, out);
}

// Round 6
// 2319.806 us; speedup vs baseline: 1.0243x; 1.0243x over previous
//
#include <hip/hip_runtime.h>
#include <hip/hip_bf16.h>

#define BB 512
#define SS 2048
#define VV 29
#define HH 128
#define NR 8             // batch rows per block (= MFMA col pairs)
#define NBLK (BB / NR)   // 64 blocks

typedef __attribute__((ext_vector_type(8))) short bf16x8;  // 8 bf16 (4 VGPRs)
typedef __attribute__((ext_vector_type(4))) float f32x4;

__device__ __forceinline__ float fast_tanh(float z) {
    float az = fabsf(z);
    float e  = __expf(-2.0f * az);
    float r  = 1.0f - 2.0f * e * __builtin_amdgcn_rcpf(1.0f + e);
    return copysignf(r, z);
}

__device__ __forceinline__ unsigned bf16_rne(float f) {   // f32 -> bf16 bits (RNE)
    unsigned u = __float_as_uint(f);
    return (u + 0x7fffu + ((u >> 16) & 1u)) >> 16;
}
__device__ __forceinline__ float bfbits2f(unsigned b) { return __uint_as_float(b << 16); }

__device__ __forceinline__ bf16x8 as_bf16x8(uint4 v) {
    union { uint4 q; bf16x8 s; } u; u.q = v; return u.s;
}

// split 8 f32 into hi/lo bf16 fragments (hi+lo reproduces f32 to ~2^-17)
__device__ __forceinline__ void pack_hilo8(const float* v, bf16x8& hi, bf16x8& lo) {
    union { unsigned u[4]; bf16x8 s; } H, L;
    #pragma unroll
    for (int p = 0; p < 4; ++p) {
        unsigned h0 = bf16_rne(v[2*p]),  h1 = bf16_rne(v[2*p+1]);
        unsigned m0 = bf16_rne(v[2*p]   - bfbits2f(h0));
        unsigned m1 = bf16_rne(v[2*p+1] - bfbits2f(h1));
        H.u[p] = h0 | (h1 << 16);
        L.u[p] = m0 | (m1 << 16);
    }
    hi = H.s; lo = L.s;
}

// x pair loader: lane p<14 -> {x[2p],x[2p+1]}, lane 14 -> {x[28],0}, else 0
__device__ __forceinline__ float2 xload(const float* xw, int t, int l) {
    float2 f = make_float2(0.f, 0.f);
    int base = t * VV + 2 * l;
    if (l < 14)       { f.x = xw[base]; f.y = xw[base + 1]; }
    else if (l == 14) { f.x = xw[base]; }
    return f;
}

__device__ __forceinline__ void xstore(unsigned* dhi, unsigned* dlo, int l, float2 f) {
    if (l < 16) {
        unsigned h0 = bf16_rne(f.x), h1 = bf16_rne(f.y);
        unsigned m0 = bf16_rne(f.x - bfbits2f(h0));
        unsigned m1 = bf16_rne(f.y - bfbits2f(h1));
        dhi[l] = h0 | (h1 << 16);
        dlo[l] = m0 | (m1 << 16);
    }
}

// 64 blocks x 512 threads (8 waves). Block handles 8 batch rows; wave w owns
// h-output rows 16w..16w+15 (one 16x16x32 M-tile) for ALL 8 batch rows.
// Encoder step = MFMA: D = [Whh_hi|lo]·B + [Weih_hi|lo]·Bx, where B's 16 cols
// are (h_hi(row r), h_lo(row r)) pairs -> col-pair sum via shfl_xor(s,1) gives
// the exact f32 product of rounded factors (incl lo·lo). 10 MFMA + 1 barrier
// per wave-step; h moves between steps as bf16 hi/lo pairs in LDS (5 b128
// reads/wave-step) instead of the ~128 b128 broadcast-instr/CU-step floor that
// bound all VALU variants (R2-R5 calibration).
// Decoder: 8 waves decode the block's 8 rows; readlane broadcast (no LDS),
// fixed-point shortcut + coalesced dwordx4 bulk fill (unchanged from R2).
__global__ __launch_bounds__(512, 2) void rnn_fused(
    const float* __restrict__ x,      // (B,S,V)
    const float* __restrict__ We_ih,  // (H,V)
    const float* __restrict__ We_hh,  // (H,H)
    const float* __restrict__ be_ih,  // (H)
    const float* __restrict__ be_hh,  // (H)
    const float* __restrict__ Wd_ih,  // (V,H)
    const float* __restrict__ Wd_hh,  // (V,V)
    const float* __restrict__ bd_ih,  // (V)
    const float* __restrict__ bd_hh,  // (V)
    float* __restrict__ out)          // (B,S,V)
{
    const int tid   = threadIdx.x;
    const int w     = tid >> 6;        // wave 0..7
    const int l     = tid & 63;        // lane
    const int c     = l & 15;          // MFMA col
    const int g     = l >> 4;          // k-group (k = 32kt + 8g + j)
    const int sel   = c & 1;           // 0 = hi operand col, 1 = lo
    const int browc = c >> 1;          // batch row this col belongs to
    const int b0    = blockIdx.x * NR;

    // [buf][hilo][brow][pair]; stride 68 (=64+4) breaks bank aliasing
    __shared__ unsigned sh_h[2][2][NR][68];
    __shared__ unsigned sh_x[2][2][NR][20];
    __shared__ float hdec[NR][HH];

    // ---- prologue: A-fragments (hi/lo) in registers ----
    bf16x8 a_hi[4], a_lo[4], ax_hi, ax_lo;
    {
        const int m = 16 * w + c;                    // A row = lane&15
        const float* ar = We_hh + (size_t)m * HH;
        #pragma unroll
        for (int kt = 0; kt < 4; ++kt) {
            float v[8];
            #pragma unroll
            for (int j = 0; j < 8; ++j) v[j] = ar[32 * kt + 8 * g + j];
            pack_hilo8(v, a_hi[kt], a_lo[kt]);
        }
        float vx[8];
        #pragma unroll
        for (int j = 0; j < 8; ++j) {
            int k = 8 * g + j;
            vx[j] = (k < VV) ? We_ih[(size_t)m * VV + k] : 0.f;
        }
        pack_hilo8(vx, ax_hi, ax_lo);
    }
    float bias4[4];
    #pragma unroll
    for (int q = 0; q < 4; ++q) {
        int row = 16 * w + 4 * g + q;
        bias4[q] = be_ih[row] + be_hh[row];
    }

    const float* xw = x + (size_t)(b0 + w) * SS * VV;   // this wave's batch row

    const unsigned* hbase = &sh_h[0][sel][browc][4 * g];
    const unsigned* xbase = &sh_x[0][sel][browc][4 * g];
    const int HSTEP = 2 * NR * 68;   // u32 delta between h buffers
    const int XSTEP = 2 * NR * 20;

    // ---- init: h0 = 0, xbuf0 = cvt(x_0), prefetch x_1, x_2 ----
    for (int idx = tid; idx < 2 * NR * 68; idx += 512)
        (&sh_h[0][0][0][0])[idx] = 0u;
    {
        float2 x0 = xload(xw, 0, l);
        xstore(&sh_x[0][0][w][0], &sh_x[0][1][w][0], l, x0);
    }
    float2 xA = xload(xw, 1, l);
    float2 xB = xload(xw, 2, l);
    __syncthreads();

    // ---- encoder scan: 2x unrolled ping-pong, ONE barrier/step ----
#define ENC_STEP(CUR, NXT, T, XREG)                                              \
    {                                                                            \
        float2 xnew;                                                             \
        { int tn = (T) + 3; if (tn >= SS) tn = SS - 1; xnew = xload(xw, tn, l); }\
        f32x4 dh = {0.f, 0.f, 0.f, 0.f}, dl = {0.f, 0.f, 0.f, 0.f};              \
        {                                                                        \
            bf16x8 bx = as_bf16x8(*(const uint4*)(xbase + (CUR) * XSTEP));       \
            dh = __builtin_amdgcn_mfma_f32_16x16x32_bf16(ax_hi, bx, dh, 0, 0, 0);\
            dl = __builtin_amdgcn_mfma_f32_16x16x32_bf16(ax_lo, bx, dl, 0, 0, 0);\
        }                                                                        \
        _Pragma("unroll")                                                        \
        for (int kt = 0; kt < 4; ++kt) {                                         \
            bf16x8 bh = as_bf16x8(*(const uint4*)(hbase + (CUR) * HSTEP + 16 * kt)); \
            dh = __builtin_amdgcn_mfma_f32_16x16x32_bf16(a_hi[kt], bh, dh, 0, 0, 0); \
            dl = __builtin_amdgcn_mfma_f32_16x16x32_bf16(a_lo[kt], bh, dl, 0, 0, 0); \
        }                                                                        \
        float hn0, hn1, hn2, hn3;                                                \
        { float s = dh[0] + dl[0]; hn0 = fast_tanh(s + __shfl_xor(s, 1, 64) + bias4[0]); } \
        { float s = dh[1] + dl[1]; hn1 = fast_tanh(s + __shfl_xor(s, 1, 64) + bias4[1]); } \
        { float s = dh[2] + dl[2]; hn2 = fast_tanh(s + __shfl_xor(s, 1, 64) + bias4[2]); } \
        { float s = dh[3] + dl[3]; hn3 = fast_tanh(s + __shfl_xor(s, 1, 64) + bias4[3]); } \
        if (!sel) {  /* even col lanes hold h_new[16w+4g+q][brow c/2] */         \
            unsigned h0 = bf16_rne(hn0), h1 = bf16_rne(hn1);                     \
            unsigned h2 = bf16_rne(hn2), h3 = bf16_rne(hn3);                     \
            unsigned m0 = bf16_rne(hn0 - bfbits2f(h0)), m1 = bf16_rne(hn1 - bfbits2f(h1)); \
            unsigned m2 = bf16_rne(hn2 - bfbits2f(h2)), m3 = bf16_rne(hn3 - bfbits2f(h3)); \
            *(uint2*)&sh_h[NXT][0][browc][8 * w + 2 * g] = make_uint2(h0 | (h1 << 16), h2 | (h3 << 16)); \
            *(uint2*)&sh_h[NXT][1][browc][8 * w + 2 * g] = make_uint2(m0 | (m1 << 16), m2 | (m3 << 16)); \
        }                                                                        \
        xstore(&sh_x[NXT][0][w][0], &sh_x[NXT][1][w][0], l, XREG);               \
        XREG = xnew;                                                             \
        __syncthreads();                                                         \
    }

    for (int t = 0; t < SS; t += 2) {
        ENC_STEP(0, 1, t,     xA)
        ENC_STEP(1, 0, t + 1, xB)
    }
    // final h (hi/lo bf16 pairs) in sh_h[0]

    // ---- decoder: wave w decodes batch row b0+w ----
    {
        unsigned uh = sh_h[0][0][w][l];
        unsigned um = sh_h[0][1][w][l];
        float h0 = bfbits2f(uh & 0xffffu) + bfbits2f(um & 0xffffu);
        float h1 = __uint_as_float(uh & 0xffff0000u) + __uint_as_float(um & 0xffff0000u);
        hdec[w][2 * l]     = h0;
        hdec[w][2 * l + 1] = h1;
    }
    __syncthreads();

    const int lane = l;
    const int r = (lane < VV) ? lane : (VV - 1);   // lanes >=29 mirror row 28

    float di = bd_ih[r] + bd_hh[r];
    {
        const float* wdi = Wd_ih + r * HH;
        const float* hv  = hdec[w];
        float d0 = 0.f, d1 = 0.f, d2 = 0.f, d3 = 0.f;
        #pragma unroll
        for (int j = 0; j < HH; j += 4) {
            d0 += wdi[j + 0] * hv[j + 0];
            d1 += wdi[j + 1] * hv[j + 1];
            d2 += wdi[j + 2] * hv[j + 2];
            d3 += wdi[j + 3] * hv[j + 3];
        }
        di += (d0 + d1) + (d2 + d3);
    }

    float wd[VV];
    {
        const float* wdr = Wd_hh + r * VV;
        #pragma unroll
        for (int j = 0; j < VV; ++j) wd[j] = wdr[j];
    }

    float hd = 0.0f;
    float* ob = out + (size_t)(b0 + w) * SS * VV;
    int t = 0;
    for (; t < SS; ++t) {
        float a0 = di, a1 = 0.f, a2 = 0.f, a3 = 0.f;
        int hbits = __float_as_int(hd);
        #pragma unroll
        for (int j = 0; j < VV; j += 4) {
            a0 += wd[j] * __int_as_float(__builtin_amdgcn_readlane(hbits, j));
            if (j + 1 < VV) a1 += wd[j + 1] * __int_as_float(__builtin_amdgcn_readlane(hbits, j + 1));
            if (j + 2 < VV) a2 += wd[j + 2] * __int_as_float(__builtin_amdgcn_readlane(hbits, j + 2));
            if (j + 3 < VV) a3 += wd[j + 3] * __int_as_float(__builtin_amdgcn_readlane(hbits, j + 3));
        }
        float hn = fast_tanh((a0 + a1) + (a2 + a3));
        int conv = (fabsf(hn - hd) < 1e-6f) ? 1 : 0;
        hd = hn;
        if (lane < VV) ob[(size_t)t * VV + lane] = hn;
        if (__all(conv)) { ++t; break; }
    }

    // ---- fixed-point bulk fill for remaining steps ----
    if (t < SS) {
        while (t & 3) {                       // align flat offset to 16B
            if (lane < VV) ob[(size_t)t * VV + lane] = hd;
            ++t;
        }
        if (t < SS) {
            // 58 lanes x float4 = 232/sweep; 232%29==0 && 232%4==0 -> exact tiling
            const int phi = (4 * lane) % VV;
            float4 v4;
            v4.x = __shfl(hd, phi, 64);
            v4.y = __shfl(hd, (phi + 1) % VV, 64);
            v4.z = __shfl(hd, (phi + 2) % VV, 64);
            v4.w = __shfl(hd, (phi + 3) % VV, 64);
            if (lane < 58) {
                const long fend = (long)SS * VV;
                for (long f = (long)t * VV + 4 * lane; f + 4 <= fend; f += 232) {
                    *reinterpret_cast<float4*>(ob + f) = v4;
                }
            }
        }
    }
}

extern "C" void kernel_launch(void* const* d_in, const int* in_sizes, int n_in,
                              void* d_out, int out_size, void* d_ws, size_t ws_size,
                              hipStream_t stream) {
    const float* x     = (const float*)d_in[0];
    const float* We_ih = (const float*)d_in[1];
    const float* We_hh = (const float*)d_in[2];
    const float* be_ih = (const float*)d_in[3];
    const float* be_hh = (const float*)d_in[4];
    const float* Wd_ih = (const float*)d_in[5];
    const float* Wd_hh = (const float*)d_in[6];
    const float* bd_ih = (const float*)d_in[7];
    const float* bd_hh = (const float*)d_in[8];
    float* out = (float*)d_out;

    rnn_fused<<<dim3(NBLK), dim3(512), 0, stream>>>(
        x, We_ih, We_hh, be_ih, be_hh, Wd_ih, Wd_hh, bd_ih, bd_hh, out);
}

// Round 7
// 1762.253 us; speedup vs baseline: 1.3484x; 1.3164x over previous
//
#include <hip/hip_runtime.h>
#include <hip/hip_bf16.h>

#define BB 512
#define SS 2048
#define VV 29
#define HH 128
#define NR 8             // batch rows per block (= MFMA col pairs)
#define NBLK (BB / NR)   // 64 blocks
#define CH 16            // x-staging chunk (steps)

typedef __attribute__((ext_vector_type(8))) short bf16x8;  // 8 bf16 (4 VGPRs)
typedef __attribute__((ext_vector_type(4))) float f32x4;

__device__ __forceinline__ float fast_tanh(float z) {
    float az = fabsf(z);
    float e  = __expf(-2.0f * az);
    float r  = 1.0f - 2.0f * e * __builtin_amdgcn_rcpf(1.0f + e);
    return copysignf(r, z);
}

__device__ __forceinline__ unsigned bf16_rne(float f) {   // f32 -> bf16 bits (RNE)
    unsigned u = __float_as_uint(f);
    return (u + 0x7fffu + ((u >> 16) & 1u)) >> 16;
}
__device__ __forceinline__ float bfbits2f(unsigned b) { return __uint_as_float(b << 16); }

__device__ __forceinline__ bf16x8 as_bf16x8(uint4 v) {
    union { uint4 q; bf16x8 s; } u; u.q = v; return u.s;
}

// split 8 f32 into hi/lo bf16 fragments (hi+lo reproduces f32 to ~2^-17)
__device__ __forceinline__ void pack_hilo8(const float* v, bf16x8& hi, bf16x8& lo) {
    union { unsigned u[4]; bf16x8 s; } H, L;
    #pragma unroll
    for (int p = 0; p < 4; ++p) {
        unsigned h0 = bf16_rne(v[2*p]),  h1 = bf16_rne(v[2*p+1]);
        unsigned m0 = bf16_rne(v[2*p]   - bfbits2f(h0));
        unsigned m1 = bf16_rne(v[2*p+1] - bfbits2f(h1));
        H.u[p] = h0 | (h1 << 16);
        L.u[p] = m0 | (m1 << 16);
    }
    hi = H.s; lo = L.s;
}

__device__ __forceinline__ void xstore(unsigned* dhi, unsigned* dlo, int l, float2 f) {
    if (l < 16) {
        unsigned h0 = bf16_rne(f.x), h1 = bf16_rne(f.y);
        unsigned m0 = bf16_rne(f.x - bfbits2f(h0));
        unsigned m1 = bf16_rne(f.y - bfbits2f(h1));
        dhi[l] = h0 | (h1 << 16);
        dlo[l] = m0 | (m1 << 16);
    }
}

// 64 blocks x 512 threads (8 waves). Block = 8 batch rows; wave w owns h-rows
// 16w..16w+15 for all 8 rows. Encoder step = 10 MFMA (hi/lo column-pair trick,
// verified R6: col-pair sum via shfl_xor(1) = exact f32-of-rounded product).
// R7 CHANGE: x is staged to LDS in 16-step raw-f32 chunks (wave w copies its
// own row, double-buffered). Per-step conversion lanes read the raw pair from
// LDS. This removes ALL per-step global loads: the compiler's mandatory
// s_waitcnt vmcnt(0) before each s_barrier (the R6 killer: fresh ~600-900cy
// x-load drained EVERY step) now waits on nothing for 15 of 16 steps; the
// single staging stall amortizes to ~40 cy/step.
// Decoder: 8 waves decode the block's 8 rows; readlane broadcast, fixed-point
// shortcut + coalesced dwordx4 bulk fill (verified R2/R6).
__global__ __launch_bounds__(512, 2) void rnn_fused(
    const float* __restrict__ x,      // (B,S,V)
    const float* __restrict__ We_ih,  // (H,V)
    const float* __restrict__ We_hh,  // (H,H)
    const float* __restrict__ be_ih,  // (H)
    const float* __restrict__ be_hh,  // (H)
    const float* __restrict__ Wd_ih,  // (V,H)
    const float* __restrict__ Wd_hh,  // (V,V)
    const float* __restrict__ bd_ih,  // (V)
    const float* __restrict__ bd_hh,  // (V)
    float* __restrict__ out)          // (B,S,V)
{
    const int tid   = threadIdx.x;
    const int w     = tid >> 6;        // wave 0..7
    const int l     = tid & 63;        // lane
    const int c     = l & 15;          // MFMA col
    const int g     = l >> 4;          // k-group (k = 32kt + 8g + j)
    const int sel   = c & 1;           // 0 = hi operand col, 1 = lo
    const int browc = c >> 1;          // batch row this col belongs to
    const int b0    = blockIdx.x * NR;

    __shared__ unsigned sh_h[2][2][NR][68];   // [buf][hilo][brow][pair]
    __shared__ unsigned sh_x[2][2][NR][20];
    __shared__ float    sh_xraw[2][NR][CH * VV];  // raw f32 x chunks
    __shared__ float    hdec[NR][HH];

    // ---- prologue: A-fragments (hi/lo) in registers ----
    bf16x8 a_hi[4], a_lo[4], ax_hi, ax_lo;
    {
        const int m = 16 * w + c;                    // A row = lane&15
        const float* ar = We_hh + (size_t)m * HH;
        #pragma unroll
        for (int kt = 0; kt < 4; ++kt) {
            float v[8];
            #pragma unroll
            for (int j = 0; j < 8; ++j) v[j] = ar[32 * kt + 8 * g + j];
            pack_hilo8(v, a_hi[kt], a_lo[kt]);
        }
        float vx[8];
        #pragma unroll
        for (int j = 0; j < 8; ++j) {
            int k = 8 * g + j;
            vx[j] = (k < VV) ? We_ih[(size_t)m * VV + k] : 0.f;
        }
        pack_hilo8(vx, ax_hi, ax_lo);
    }
    float bias4[4];
    #pragma unroll
    for (int q = 0; q < 4; ++q) {
        int row = 16 * w + 4 * g + q;
        bias4[q] = be_ih[row] + be_hh[row];
    }

    const float* xw = x + (size_t)(b0 + w) * SS * VV;   // this wave's batch row

    const unsigned* hbase = &sh_h[0][sel][browc][4 * g];
    const unsigned* xbase = &sh_x[0][sel][browc][4 * g];
    const int HSTEP = 2 * NR * 68;   // u32 delta between h buffers
    const int XSTEP = 2 * NR * 20;

    // ---- init: h0 = 0; stage chunk 0 raw; convert step-0 x frag ----
    for (int idx = tid; idx < 2 * NR * 68; idx += 512)
        (&sh_h[0][0][0][0])[idx] = 0u;
    {
        float* raw = &sh_xraw[0][w][0];
        for (int j = l; j < CH * VV; j += 64) raw[j] = xw[j];
    }
    __syncthreads();
    {
        const float* rb = &sh_xraw[0][w][0];
        float2 f = make_float2(0.f, 0.f);
        if (l < 14)       { f.x = rb[2 * l]; f.y = rb[2 * l + 1]; }
        else if (l == 14) { f.x = rb[2 * l]; }
        xstore(&sh_x[0][0][w][0], &sh_x[0][1][w][0], l, f);
    }
    __syncthreads();

    // ---- encoder scan: 2x unrolled ping-pong, ONE barrier/step ----
#define ENC_STEP(CUR, NXT, T)                                                    \
    {                                                                            \
        /* convert next step's x-frag from raw LDS (lanes<16, own row) */        \
        {                                                                        \
            int tn = (T) + 1; if (tn >= SS) tn = SS - 1;                         \
            const float* rb = &sh_xraw[(tn >> 4) & 1][w][(tn & 15) * VV];        \
            float2 f = make_float2(0.f, 0.f);                                    \
            if (l < 14)       { f.x = rb[2 * l]; f.y = rb[2 * l + 1]; }          \
            else if (l == 14) { f.x = rb[2 * l]; }                               \
            xstore(&sh_x[NXT][0][w][0], &sh_x[NXT][1][w][0], l, f);              \
        }                                                                        \
        f32x4 dh = {0.f, 0.f, 0.f, 0.f}, dl = {0.f, 0.f, 0.f, 0.f};              \
        {                                                                        \
            bf16x8 bx = as_bf16x8(*(const uint4*)(xbase + (CUR) * XSTEP));       \
            dh = __builtin_amdgcn_mfma_f32_16x16x32_bf16(ax_hi, bx, dh, 0, 0, 0);\
            dl = __builtin_amdgcn_mfma_f32_16x16x32_bf16(ax_lo, bx, dl, 0, 0, 0);\
        }                                                                        \
        _Pragma("unroll")                                                        \
        for (int kt = 0; kt < 4; ++kt) {                                         \
            bf16x8 bh = as_bf16x8(*(const uint4*)(hbase + (CUR) * HSTEP + 16 * kt)); \
            dh = __builtin_amdgcn_mfma_f32_16x16x32_bf16(a_hi[kt], bh, dh, 0, 0, 0); \
            dl = __builtin_amdgcn_mfma_f32_16x16x32_bf16(a_lo[kt], bh, dl, 0, 0, 0); \
        }                                                                        \
        float hn0, hn1, hn2, hn3;                                                \
        { float s = dh[0] + dl[0]; hn0 = fast_tanh(s + __shfl_xor(s, 1, 64) + bias4[0]); } \
        { float s = dh[1] + dl[1]; hn1 = fast_tanh(s + __shfl_xor(s, 1, 64) + bias4[1]); } \
        { float s = dh[2] + dl[2]; hn2 = fast_tanh(s + __shfl_xor(s, 1, 64) + bias4[2]); } \
        { float s = dh[3] + dl[3]; hn3 = fast_tanh(s + __shfl_xor(s, 1, 64) + bias4[3]); } \
        if (!sel) {  /* even col lanes hold h_new[16w+4g+q][brow c/2] */         \
            unsigned h0 = bf16_rne(hn0), h1 = bf16_rne(hn1);                     \
            unsigned h2 = bf16_rne(hn2), h3 = bf16_rne(hn3);                     \
            unsigned m0 = bf16_rne(hn0 - bfbits2f(h0)), m1 = bf16_rne(hn1 - bfbits2f(h1)); \
            unsigned m2 = bf16_rne(hn2 - bfbits2f(h2)), m3 = bf16_rne(hn3 - bfbits2f(h3)); \
            *(uint2*)&sh_h[NXT][0][browc][8 * w + 2 * g] = make_uint2(h0 | (h1 << 16), h2 | (h3 << 16)); \
            *(uint2*)&sh_h[NXT][1][browc][8 * w + 2 * g] = make_uint2(m0 | (m1 << 16), m2 | (m3 << 16)); \
        }                                                                        \
        __syncthreads();                                                         \
    }

    for (int tc = 0; tc < SS; tc += CH) {
        const int cb = (tc >> 4) & 1;
        // stage NEXT chunk (wave w copies its own row; only global ops in the
        // whole chunk -> one amortized vmcnt stall per 16 steps)
        if (tc + CH < SS) {
            const float* xs = xw + (size_t)(tc + CH) * VV;
            float* raw = &sh_xraw[cb ^ 1][w][0];
            for (int j = l; j < CH * VV; j += 64) raw[j] = xs[j];
        }
        for (int s = 0; s < CH; s += 2) {
            ENC_STEP(0, 1, tc + s)
            ENC_STEP(1, 0, tc + s + 1)
        }
    }
    // final h (hi/lo bf16 pairs) in sh_h[0]

    // ---- decoder: wave w decodes batch row b0+w ----
    {
        unsigned uh = sh_h[0][0][w][l];
        unsigned um = sh_h[0][1][w][l];
        float h0 = bfbits2f(uh & 0xffffu) + bfbits2f(um & 0xffffu);
        float h1 = __uint_as_float(uh & 0xffff0000u) + __uint_as_float(um & 0xffff0000u);
        hdec[w][2 * l]     = h0;
        hdec[w][2 * l + 1] = h1;
    }
    __syncthreads();

    const int lane = l;
    const int r = (lane < VV) ? lane : (VV - 1);   // lanes >=29 mirror row 28

    float di = bd_ih[r] + bd_hh[r];
    {
        const float* wdi = Wd_ih + r * HH;
        const float* hv  = hdec[w];
        float d0 = 0.f, d1 = 0.f, d2 = 0.f, d3 = 0.f;
        #pragma unroll
        for (int j = 0; j < HH; j += 4) {
            d0 += wdi[j + 0] * hv[j + 0];
            d1 += wdi[j + 1] * hv[j + 1];
            d2 += wdi[j + 2] * hv[j + 2];
            d3 += wdi[j + 3] * hv[j + 3];
        }
        di += (d0 + d1) + (d2 + d3);
    }

    float wd[VV];
    {
        const float* wdr = Wd_hh + r * VV;
        #pragma unroll
        for (int j = 0; j < VV; ++j) wd[j] = wdr[j];
    }

    float hd = 0.0f;
    float* ob = out + (size_t)(b0 + w) * SS * VV;
    int t = 0;
    for (; t < SS; ++t) {
        float a0 = di, a1 = 0.f, a2 = 0.f, a3 = 0.f;
        int hbits = __float_as_int(hd);
        #pragma unroll
        for (int j = 0; j < VV; j += 4) {
            a0 += wd[j] * __int_as_float(__builtin_amdgcn_readlane(hbits, j));
            if (j + 1 < VV) a1 += wd[j + 1] * __int_as_float(__builtin_amdgcn_readlane(hbits, j + 1));
            if (j + 2 < VV) a2 += wd[j + 2] * __int_as_float(__builtin_amdgcn_readlane(hbits, j + 2));
            if (j + 3 < VV) a3 += wd[j + 3] * __int_as_float(__builtin_amdgcn_readlane(hbits, j + 3));
        }
        float hn = fast_tanh((a0 + a1) + (a2 + a3));
        int conv = (fabsf(hn - hd) < 1e-6f) ? 1 : 0;
        hd = hn;
        if (lane < VV) ob[(size_t)t * VV + lane] = hn;
        if (__all(conv)) { ++t; break; }
    }

    // ---- fixed-point bulk fill for remaining steps ----
    if (t < SS) {
        while (t & 3) {                       // align flat offset to 16B
            if (lane < VV) ob[(size_t)t * VV + lane] = hd;
            ++t;
        }
        if (t < SS) {
            // 58 lanes x float4 = 232/sweep; 232%29==0 && 232%4==0 -> exact tiling
            const int phi = (4 * lane) % VV;
            float4 v4;
            v4.x = __shfl(hd, phi, 64);
            v4.y = __shfl(hd, (phi + 1) % VV, 64);
            v4.z = __shfl(hd, (phi + 2) % VV, 64);
            v4.w = __shfl(hd, (phi + 3) % VV, 64);
            if (lane < 58) {
                const long fend = (long)SS * VV;
                for (long f = (long)t * VV + 4 * lane; f + 4 <= fend; f += 232) {
                    *reinterpret_cast<float4*>(ob + f) = v4;
                }
            }
        }
    }
}

extern "C" void kernel_launch(void* const* d_in, const int* in_sizes, int n_in,
                              void* d_out, int out_size, void* d_ws, size_t ws_size,
                              hipStream_t stream) {
    const float* x     = (const float*)d_in[0];
    const float* We_ih = (const float*)d_in[1];
    const float* We_hh = (const float*)d_in[2];
    const float* be_ih = (const float*)d_in[3];
    const float* be_hh = (const float*)d_in[4];
    const float* Wd_ih = (const float*)d_in[5];
    const float* Wd_hh = (const float*)d_in[6];
    const float* bd_ih = (const float*)d_in[7];
    const float* bd_hh = (const float*)d_in[8];
    float* out = (float*)d_out;

    rnn_fused<<<dim3(NBLK), dim3(512), 0, stream>>>(
        x, We_ih, We_hh, be_ih, be_hh, Wd_ih, Wd_hh, bd_ih, bd_hh, out);
}

// Round 8
// 1721.658 us; speedup vs baseline: 1.3802x; 1.0236x over previous
//
#include <hip/hip_runtime.h>
#include <hip/hip_bf16.h>

#define BB 512
#define SS 2048
#define VV 29
#define HH 128
#define CH 16

typedef __attribute__((ext_vector_type(8))) short bf16x8;
typedef __attribute__((ext_vector_type(4))) float f32x4;

__device__ __forceinline__ float fast_tanh(float z) {
    float az = fabsf(z);
    float e  = __expf(-2.0f * az);
    float r  = 1.0f - 2.0f * e * __builtin_amdgcn_rcpf(1.0f + e);
    return copysignf(r, z);
}
__device__ __forceinline__ unsigned bf16_rne(float f) {   // f32 -> bf16 bits (RNE)
    unsigned u = __float_as_uint(f);
    return (u + 0x7fffu + ((u >> 16) & 1u)) >> 16;
}
__device__ __forceinline__ float bfbits2f(unsigned b) { return __uint_as_float(b << 16); }
__device__ __forceinline__ bf16x8 as_bf16x8(uint4 v) { union { uint4 q; bf16x8 s; } u; u.q = v; return u.s; }

#define MF(A, B, C) __builtin_amdgcn_mfma_f32_16x16x32_bf16((A), (B), (C), 0, 0, 0)

// Raw barrier: no vmcnt drain (keeps chunk x-prefetch in flight across steps).
#define BLOCK_SYNC do {                                        \
    asm volatile("s_waitcnt lgkmcnt(0)" ::: "memory");         \
    __builtin_amdgcn_s_barrier();                              \
    asm volatile("" ::: "memory");                             \
} while (0)

// 512 blocks (one per batch row) x 256 threads (4 waves) -> 2 blocks/CU
// co-resident: independent recurrences hide each other's chain stalls.
// Wave w owns output rows 32w..32w+31 (M-tiles 2w, 2w+1).
// Encoder step: 30 MFMA (15 K-tiles x 2 M-tiles), 3-term hi/lo precision:
//   hi-pass (8 h-tiles + 2 x-tiles): A word = Whi|Wlo, B word = hhi|hhi
//     -> (Whi+Wlo)*hhi
//   lo-pass (4 h-tiles + 1 x-tile):  A word = Whi0|Whi1, B shorts = hlo
//     -> Whi*hlo          (dropped Wlo*hlo ~ 4e-5 total, negligible)
// All lanes read c-independent B (16 identical cols -> broadcast, real data
// in every lane); lanes c==0 / c==8 publish tiles 2w / 2w+1. Bias rides as
// MFMA C-in. x is converted to fragments once per 16-step chunk; loads are
// issued a chunk ahead into registers (issue-early/write-late).
__global__ __launch_bounds__(256, 2) void rnn_fused(
    const float* __restrict__ x,      // (B,S,V)
    const float* __restrict__ We_ih,  // (H,V)
    const float* __restrict__ We_hh,  // (H,H)
    const float* __restrict__ be_ih,  // (H)
    const float* __restrict__ be_hh,  // (H)
    const float* __restrict__ Wd_ih,  // (V,H)
    const float* __restrict__ Wd_hh,  // (V,V)
    const float* __restrict__ bd_ih,  // (V)
    const float* __restrict__ bd_hh,  // (V)
    float* __restrict__ out)          // (B,S,V)
{
    const int tid = threadIdx.x;
    const int w   = tid >> 6;          // wave 0..3
    const int l   = tid & 63;
    const int c   = l & 15;            // MFMA col
    const int g   = l >> 4;            // k-group
    const int b   = blockIdx.x;        // batch row

    __shared__ uint4    shBhi[2][8][4];        // h hi-pass frags [buf][kt][g]
    __shared__ unsigned shBlo[2][64];          // h lo shorts (word e>>1)
    __shared__ uint4    shBxhi[2][CH][2][4];   // x hi-pass frags [cb][t][xt][g]
    __shared__ unsigned shBxlo[2][CH][16];     // x lo shorts
    __shared__ float    hdec[HH];

    // ---------------- A fragments (prologue) ----------------
    bf16x8 a0[15], a1[15];
    {
        const int m0 = 16 * (2 * w)     + c;
        const int m1 = 16 * (2 * w + 1) + c;
        const float* r0 = We_hh + m0 * HH;
        const float* r1 = We_hh + m1 * HH;
        #pragma unroll
        for (int kt = 0; kt < 8; ++kt) {       // h hi-pass: Whi|Wlo of e=16kt+4g+p
            union { unsigned u[4]; bf16x8 s; } U0, U1;
            #pragma unroll
            for (int p = 0; p < 4; ++p) {
                int e = 16 * kt + 4 * g + p;
                { float f = r0[e]; unsigned hi = bf16_rne(f); unsigned lo = bf16_rne(f - bfbits2f(hi)); U0.u[p] = hi | (lo << 16); }
                { float f = r1[e]; unsigned hi = bf16_rne(f); unsigned lo = bf16_rne(f - bfbits2f(hi)); U1.u[p] = hi | (lo << 16); }
            }
            a0[kt] = U0.s; a1[kt] = U1.s;
        }
        #pragma unroll
        for (int lt = 0; lt < 4; ++lt) {       // h lo-pass: Whi pairs, e0=32lt+8g+2p
            union { unsigned u[4]; bf16x8 s; } U0, U1;
            #pragma unroll
            for (int p = 0; p < 4; ++p) {
                int e0 = 32 * lt + 8 * g + 2 * p;
                U0.u[p] = bf16_rne(r0[e0]) | (bf16_rne(r0[e0 + 1]) << 16);
                U1.u[p] = bf16_rne(r1[e0]) | (bf16_rne(r1[e0 + 1]) << 16);
            }
            a0[8 + lt] = U0.s; a1[8 + lt] = U1.s;
        }
        const float* q0 = We_ih + m0 * VV;
        const float* q1 = We_ih + m1 * VV;
        #pragma unroll
        for (int xt = 0; xt < 2; ++xt) {       // x hi-pass
            union { unsigned u[4]; bf16x8 s; } U0, U1;
            #pragma unroll
            for (int p = 0; p < 4; ++p) {
                int e = 16 * xt + 4 * g + p;
                float f0 = (e < VV) ? q0[e] : 0.f;
                float f1 = (e < VV) ? q1[e] : 0.f;
                { unsigned hi = bf16_rne(f0); unsigned lo = bf16_rne(f0 - bfbits2f(hi)); U0.u[p] = hi | (lo << 16); }
                { unsigned hi = bf16_rne(f1); unsigned lo = bf16_rne(f1 - bfbits2f(hi)); U1.u[p] = hi | (lo << 16); }
            }
            a0[12 + xt] = U0.s; a1[12 + xt] = U1.s;
        }
        {                                      // x lo-pass (1 tile)
            union { unsigned u[4]; bf16x8 s; } U0, U1;
            #pragma unroll
            for (int p = 0; p < 4; ++p) {
                int e0 = 8 * g + 2 * p;
                float f00 = (e0     < VV) ? q0[e0]     : 0.f;
                float f01 = (e0 + 1 < VV) ? q0[e0 + 1] : 0.f;
                float f10 = (e0     < VV) ? q1[e0]     : 0.f;
                float f11 = (e0 + 1 < VV) ? q1[e0 + 1] : 0.f;
                U0.u[p] = bf16_rne(f00) | (bf16_rne(f01) << 16);
                U1.u[p] = bf16_rne(f10) | (bf16_rne(f11) << 16);
            }
            a0[14] = U0.s; a1[14] = U1.s;
        }
    }

    f32x4 bias0v, bias1v;                      // MFMA C-in (chain a)
    #pragma unroll
    for (int q = 0; q < 4; ++q) {
        int r0 = 16 * (2 * w)     + 4 * g + q;
        int r1 = 16 * (2 * w + 1) + 4 * g + q;
        bias0v[q] = be_ih[r0] + be_hh[r0];
        bias1v[q] = be_ih[r1] + be_hh[r1];
    }

    // ---------------- x staging / conversion ----------------
    const float* xrow = x + (size_t)b * SS * VV;
    float xr0 = 0.f, xr1 = 0.f;

#define XLOAD(CHUNK) {                                                          \
        const float* p_ = xrow + (CHUNK) * (CH * VV);                           \
        xr0 = p_[tid];                                                          \
        if (tid < CH * VV - 256) xr1 = p_[tid + 256]; }

#define XCONVERT(CB) {                                                          \
        { int idx = tid; int t_ = idx / VV; int e_ = idx - VV * t_;             \
          unsigned hi = bf16_rne(xr0); unsigned lo = bf16_rne(xr0 - bfbits2f(hi)); \
          ((unsigned*)&shBxhi[CB][t_][0][0])[(e_ >> 4) * 16 + ((e_ >> 2) & 3) * 4 + (e_ & 3)] = hi | (hi << 16); \
          ((unsigned short*)&shBxlo[CB][t_][0])[e_] = (unsigned short)lo; }     \
        if (tid < CH * VV - 256) {                                              \
          int idx = tid + 256; int t_ = idx / VV; int e_ = idx - VV * t_;       \
          unsigned hi = bf16_rne(xr1); unsigned lo = bf16_rne(xr1 - bfbits2f(hi)); \
          ((unsigned*)&shBxhi[CB][t_][0][0])[(e_ >> 4) * 16 + ((e_ >> 2) & 3) * 4 + (e_ & 3)] = hi | (hi << 16); \
          ((unsigned short*)&shBxlo[CB][t_][0])[e_] = (unsigned short)lo; } }

    {   // zero-init (h0 = 0; pad slots of x frags stay 0 forever)
        const uint4 z = make_uint4(0u, 0u, 0u, 0u);
        ((uint4*)shBxhi)[tid] = z;                 // 256 uint4
        if (tid < 64)  ((uint4*)shBhi)[tid]  = z;  // both h-hi buffers
        if (tid < 32)  ((uint4*)shBlo)[tid]  = z;  // both h-lo buffers
        if (tid < 128) ((uint4*)shBxlo)[tid] = z;  // both x-lo buffers
    }
    XLOAD(0);
    __syncthreads();
    XCONVERT(0);
    XLOAD(1);
    BLOCK_SYNC;

    // ---------------- encoder step ----------------
#define ENC_STEP(CUR, NXT, SLOC, CB)                                            \
    {                                                                           \
        const uint4* bp  = (const uint4*)shBhi + (CUR) * 32 + g;                \
        const uint4* blp = (const uint4*)((const unsigned*)shBlo + (CUR) * 64) + g; \
        const uint4* bxp = (const uint4*)shBxhi + ((CB) * CH + (SLOC)) * 8 + g; \
        const uint4* bxl = (const uint4*)((const unsigned*)shBxlo + ((CB) * CH + (SLOC)) * 16) + g; \
        bf16x8 B0  = as_bf16x8(bp[0]);                                          \
        bf16x8 B1  = as_bf16x8(bp[4]);                                          \
        bf16x8 B2  = as_bf16x8(bp[8]);                                          \
        bf16x8 B3  = as_bf16x8(bp[12]);                                         \
        bf16x8 B4  = as_bf16x8(bp[16]);                                         \
        bf16x8 B5  = as_bf16x8(bp[20]);                                         \
        bf16x8 B6  = as_bf16x8(bp[24]);                                         \
        bf16x8 B7  = as_bf16x8(bp[28]);                                         \
        bf16x8 B8  = as_bf16x8(blp[0]);                                         \
        bf16x8 B9  = as_bf16x8(blp[4]);                                         \
        bf16x8 B10 = as_bf16x8(blp[8]);                                         \
        bf16x8 B11 = as_bf16x8(blp[12]);                                        \
        bf16x8 B12 = as_bf16x8(bxp[0]);                                         \
        bf16x8 B13 = as_bf16x8(bxp[4]);                                         \
        bf16x8 B14 = as_bf16x8(bxl[0]);                                         \
        f32x4 d0a = bias0v, d0b = {0.f,0.f,0.f,0.f}, d0c = {0.f,0.f,0.f,0.f};   \
        f32x4 d1a = bias1v, d1b = {0.f,0.f,0.f,0.f}, d1c = {0.f,0.f,0.f,0.f};   \
        d0a = MF(a0[0],  B0,  d0a);  d1a = MF(a1[0],  B0,  d1a);                \
        d0b = MF(a0[1],  B1,  d0b);  d1b = MF(a1[1],  B1,  d1b);                \
        d0c = MF(a0[2],  B2,  d0c);  d1c = MF(a1[2],  B2,  d1c);                \
        d0a = MF(a0[3],  B3,  d0a);  d1a = MF(a1[3],  B3,  d1a);                \
        d0b = MF(a0[4],  B4,  d0b);  d1b = MF(a1[4],  B4,  d1b);                \
        d0c = MF(a0[5],  B5,  d0c);  d1c = MF(a1[5],  B5,  d1c);                \
        d0a = MF(a0[6],  B6,  d0a);  d1a = MF(a1[6],  B6,  d1a);                \
        d0b = MF(a0[7],  B7,  d0b);  d1b = MF(a1[7],  B7,  d1b);                \
        d0c = MF(a0[8],  B8,  d0c);  d1c = MF(a1[8],  B8,  d1c);                \
        d0a = MF(a0[9],  B9,  d0a);  d1a = MF(a1[9],  B9,  d1a);                \
        d0b = MF(a0[10], B10, d0b);  d1b = MF(a1[10], B10, d1b);                \
        d0c = MF(a0[11], B11, d0c);  d1c = MF(a1[11], B11, d1c);                \
        d0a = MF(a0[12], B12, d0a);  d1a = MF(a1[12], B12, d1a);                \
        d0b = MF(a0[13], B13, d0b);  d1b = MF(a1[13], B13, d1b);                \
        d0c = MF(a0[14], B14, d0c);  d1c = MF(a1[14], B14, d1c);                \
        const int tsel = c >> 3;                                                \
        float s0 = tsel ? (d1a[0] + d1b[0] + d1c[0]) : (d0a[0] + d0b[0] + d0c[0]); \
        float s1 = tsel ? (d1a[1] + d1b[1] + d1c[1]) : (d0a[1] + d0b[1] + d0c[1]); \
        float s2 = tsel ? (d1a[2] + d1b[2] + d1c[2]) : (d0a[2] + d0b[2] + d0c[2]); \
        float s3 = tsel ? (d1a[3] + d1b[3] + d1c[3]) : (d0a[3] + d0b[3] + d0c[3]); \
        float hn0 = fast_tanh(s0), hn1 = fast_tanh(s1);                         \
        float hn2 = fast_tanh(s2), hn3 = fast_tanh(s3);                         \
        unsigned hi0 = bf16_rne(hn0), hi1 = bf16_rne(hn1);                      \
        unsigned hi2 = bf16_rne(hn2), hi3 = bf16_rne(hn3);                      \
        unsigned lo0 = bf16_rne(hn0 - bfbits2f(hi0));                           \
        unsigned lo1 = bf16_rne(hn1 - bfbits2f(hi1));                           \
        unsigned lo2 = bf16_rne(hn2 - bfbits2f(hi2));                           \
        unsigned lo3 = bf16_rne(hn3 - bfbits2f(hi3));                           \
        if ((c & 7) == 0) {                                                     \
            int T = 2 * w + tsel;                                               \
            shBhi[NXT][T][g] = make_uint4(hi0 | (hi0 << 16), hi1 | (hi1 << 16), \
                                          hi2 | (hi2 << 16), hi3 | (hi3 << 16));\
            *(uint2*)&shBlo[NXT][8 * T + 2 * g] =                               \
                make_uint2(lo0 | (lo1 << 16), lo2 | (lo3 << 16));               \
        }                                                                       \
        BLOCK_SYNC;                                                             \
    }

    int cur = 0;
    for (int tc = 0; tc < SS; tc += CH) {
        const int cb = (tc >> 4) & 1;
        for (int s = 0; s < CH; ++s) {
            ENC_STEP(cur, cur ^ 1, s, cb)
            cur ^= 1;
        }
        if (tc + CH < SS) {
            int nc = (tc >> 4) + 1;
            XCONVERT(nc & 1);                  // xr holds chunk nc (loaded 16 steps ago)
            if (tc + 2 * CH < SS) XLOAD(nc + 1);
            BLOCK_SYNC;
        }
    }
    // 2048 steps (even) -> final h in buffers [0]

    // ---------------- decoder ----------------
    if (tid < HH) {
        unsigned wh = ((const unsigned*)shBhi)[((tid >> 4) * 4 + ((tid >> 2) & 3)) * 4 + (tid & 3)];
        unsigned wl = shBlo[0][tid >> 1];
        unsigned lo16 = (tid & 1) ? (wl >> 16) : (wl & 0xffffu);
        hdec[tid] = bfbits2f(wh & 0xffffu) + bfbits2f(lo16);
    }
    __syncthreads();
    if (tid >= 64) return;                     // waves 1..3 done (no barriers below)

    const int lane = tid;
    const int r = (lane < VV) ? lane : (VV - 1);   // lanes >=29 mirror row 28

    float di = bd_ih[r] + bd_hh[r];
    {
        const float* wdi = Wd_ih + r * HH;
        float d0 = 0.f, d1 = 0.f, d2 = 0.f, d3 = 0.f;
        #pragma unroll
        for (int j = 0; j < HH; j += 4) {
            d0 += wdi[j + 0] * hdec[j + 0];
            d1 += wdi[j + 1] * hdec[j + 1];
            d2 += wdi[j + 2] * hdec[j + 2];
            d3 += wdi[j + 3] * hdec[j + 3];
        }
        di += (d0 + d1) + (d2 + d3);
    }

    float wd[VV];
    {
        const float* wdr = Wd_hh + r * VV;
        #pragma unroll
        for (int j = 0; j < VV; ++j) wd[j] = wdr[j];
    }

    float hd = 0.0f;
    float* ob = out + (size_t)b * SS * VV;
    int t = 0;
    for (; t < SS; ++t) {
        float A0 = di, A1 = 0.f, A2 = 0.f, A3 = 0.f;
        int hbits = __float_as_int(hd);
        #pragma unroll
        for (int j = 0; j < VV; j += 4) {
            A0 += wd[j] * __int_as_float(__builtin_amdgcn_readlane(hbits, j));
            if (j + 1 < VV) A1 += wd[j + 1] * __int_as_float(__builtin_amdgcn_readlane(hbits, j + 1));
            if (j + 2 < VV) A2 += wd[j + 2] * __int_as_float(__builtin_amdgcn_readlane(hbits, j + 2));
            if (j + 3 < VV) A3 += wd[j + 3] * __int_as_float(__builtin_amdgcn_readlane(hbits, j + 3));
        }
        float hn = fast_tanh((A0 + A1) + (A2 + A3));
        int conv = (fabsf(hn - hd) < 1e-6f) ? 1 : 0;
        hd = hn;
        if (lane < VV) ob[(size_t)t * VV + lane] = hn;
        if (__all(conv)) { ++t; break; }
    }

    if (t < SS) {                              // fixed-point bulk fill
        while (t & 3) {
            if (lane < VV) ob[(size_t)t * VV + lane] = hd;
            ++t;
        }
        if (t < SS) {
            const int phi = (4 * lane) % VV;
            float4 v4;
            v4.x = __shfl(hd, phi, 64);
            v4.y = __shfl(hd, (phi + 1) % VV, 64);
            v4.z = __shfl(hd, (phi + 2) % VV, 64);
            v4.w = __shfl(hd, (phi + 3) % VV, 64);
            if (lane < 58) {
                const long fend = (long)SS * VV;
                for (long f = (long)t * VV + 4 * lane; f + 4 <= fend; f += 232) {
                    *reinterpret_cast<float4*>(ob + f) = v4;
                }
            }
        }
    }
}

extern "C" void kernel_launch(void* const* d_in, const int* in_sizes, int n_in,
                              void* d_out, int out_size, void* d_ws, size_t ws_size,
                              hipStream_t stream) {
    const float* x     = (const float*)d_in[0];
    const float* We_ih = (const float*)d_in[1];
    const float* We_hh = (const float*)d_in[2];
    const float* be_ih = (const float*)d_in[3];
    const float* be_hh = (const float*)d_in[4];
    const float* Wd_ih = (const float*)d_in[5];
    const float* Wd_hh = (const float*)d_in[6];
    const float* bd_ih = (const float*)d_in[7];
    const float* bd_hh = (const float*)d_in[8];
    float* out = (float*)d_out;

    rnn_fused<<<dim3(BB), dim3(256), 0, stream>>>(
        x, We_ih, We_hh, be_ih, be_hh, Wd_ih, Wd_hh, bd_ih, bd_hh, out);
}

// Round 9
// 1623.490 us; speedup vs baseline: 1.4636x; 1.0605x over previous
//
#include <hip/hip_runtime.h>
#include <hip/hip_bf16.h>

#define BB 512
#define SS 2048
#define VV 29
#define HH 128
#define NC 16            // batch rows (MFMA cols) per block
#define NBLK (BB / NC)   // 32 blocks
#define CH 16            // x-staging chunk (steps)

typedef __attribute__((ext_vector_type(8))) short bf16x8;
typedef __attribute__((ext_vector_type(4))) float f32x4;

__device__ __forceinline__ float fast_tanh(float z) {
    float az = fabsf(z);
    float e  = __expf(-2.0f * az);
    float r  = 1.0f - 2.0f * e * __builtin_amdgcn_rcpf(1.0f + e);
    return copysignf(r, z);
}
__device__ __forceinline__ unsigned bf16_rne(float f) {   // f32 -> bf16 bits (RNE)
    unsigned u = __float_as_uint(f);
    return (u + 0x7fffu + ((u >> 16) & 1u)) >> 16;
}
__device__ __forceinline__ float bfbits2f(unsigned b) { return __uint_as_float(b << 16); }
__device__ __forceinline__ bf16x8 as_bf16x8(uint4 v) { union { uint4 q; bf16x8 s; } u; u.q = v; return u.s; }

#define MF(A, B, C) __builtin_amdgcn_mfma_f32_16x16x32_bf16((A), (B), (C), 0, 0, 0)

// Raw barrier: lgkmcnt only (keeps next-chunk x global loads in flight).
#define BLOCK_SYNC do {                                        \
    asm volatile("s_waitcnt lgkmcnt(0)" ::: "memory");         \
    __builtin_amdgcn_s_barrier();                              \
    asm volatile("" ::: "memory");                             \
} while (0)

// 32 blocks x 256 threads (4 waves). Block = 16 batch rows carried as the 16
// REAL MFMA columns (R8 post-mortem: one 16x16x32 MFMA = ~19.4 SIMD-cycles of
// matrix pipe; R8's 16-duplicated-column B wasted 15/16 of that). Wave w owns
// h-rows 32w..32w+31 (M-tiles 2w, 2w+1). 3-term hi/lo (verified R6-R8):
//   d*a = Whi.hhi (+bias C-in), d*b = Wlo.hhi, d*c = Whi.hlo; x likewise.
// 30 MFMA/wave/step now serve all 16 rows. h moves step-to-step as bf16 hi/lo
// B-fragments in LDS; write mapping from C/D (col=lane&15,row=4g+q):
//   e=16T+4g+q -> kt=w, gB=2t'+(g>>1), word=2(g&1)+(q>>1), half=q&1
// => per lane per tile one uint2 (hi) + one uint2 (lo), conflict-free-ish.
// x pre-converted to frags one 16-step chunk ahead (R7 lesson: no per-step
// global ops -> no vmcnt drain at the per-step barrier).
// Decoder: 2 rows per wave (width-32 shuffles), 2 passes, fixed-point
// shortcut + coalesced dwordx4 bulk fill (verified R2/R6-R8).
__global__ __launch_bounds__(256, 1) void rnn_fused(
    const float* __restrict__ x,      // (B,S,V)
    const float* __restrict__ We_ih,  // (H,V)
    const float* __restrict__ We_hh,  // (H,H)
    const float* __restrict__ be_ih,  // (H)
    const float* __restrict__ be_hh,  // (H)
    const float* __restrict__ Wd_ih,  // (V,H)
    const float* __restrict__ Wd_hh,  // (V,V)
    const float* __restrict__ bd_ih,  // (V)
    const float* __restrict__ bd_hh,  // (V)
    float* __restrict__ out)          // (B,S,V)
{
    const int tid = threadIdx.x;
    const int w   = tid >> 6;          // wave 0..3
    const int l   = tid & 63;
    const int c   = l & 15;            // MFMA col == batch row within block
    const int g   = l >> 4;            // k-group
    const int b0  = blockIdx.x * NC;

    __shared__ uint4 shHhi[2][4][4][16];   // [buf][kt][gB][c]
    __shared__ uint4 shHlo[2][4][4][16];
    __shared__ uint4 shXhi[2][CH][4][17];  // [cb][t][g][c] (+pad col)
    __shared__ uint4 shXlo[2][CH][4][17];
    __shared__ float hdec[NC][HH];

    // ---------------- A fragments (prologue) ----------------
    // word p of lane (g,c), K-tile kt covers k = 32kt+8g+2p, +1; A-row m.
    bf16x8 whiA[4], wloA[4], whiB[4], wloB[4];
    bf16x8 wxhiA, wxloA, wxhiB, wxloB;
    {
        const int m0 = 16 * (2 * w)     + c;
        const int m1 = 16 * (2 * w + 1) + c;
        const float* r0 = We_hh + (size_t)m0 * HH;
        const float* r1 = We_hh + (size_t)m1 * HH;
        #pragma unroll
        for (int kt = 0; kt < 4; ++kt) {
            union { unsigned u[4]; bf16x8 s; } HA, LA, HB, LB;
            #pragma unroll
            for (int p = 0; p < 4; ++p) {
                int e0 = 32 * kt + 8 * g + 2 * p;
                float fa0 = r0[e0], fa1 = r0[e0 + 1];
                float fb0 = r1[e0], fb1 = r1[e0 + 1];
                unsigned ha0 = bf16_rne(fa0), ha1 = bf16_rne(fa1);
                unsigned hb0 = bf16_rne(fb0), hb1 = bf16_rne(fb1);
                HA.u[p] = ha0 | (ha1 << 16);
                HB.u[p] = hb0 | (hb1 << 16);
                LA.u[p] = bf16_rne(fa0 - bfbits2f(ha0)) | (bf16_rne(fa1 - bfbits2f(ha1)) << 16);
                LB.u[p] = bf16_rne(fb0 - bfbits2f(hb0)) | (bf16_rne(fb1 - bfbits2f(hb1)) << 16);
            }
            whiA[kt] = HA.s; wloA[kt] = LA.s;
            whiB[kt] = HB.s; wloB[kt] = LB.s;
        }
        const float* q0 = We_ih + (size_t)m0 * VV;
        const float* q1 = We_ih + (size_t)m1 * VV;
        union { unsigned u[4]; bf16x8 s; } HA, LA, HB, LB;
        #pragma unroll
        for (int p = 0; p < 4; ++p) {
            int k0 = 8 * g + 2 * p;
            float fa0 = (k0     < VV) ? q0[k0]     : 0.f;
            float fa1 = (k0 + 1 < VV) ? q0[k0 + 1] : 0.f;
            float fb0 = (k0     < VV) ? q1[k0]     : 0.f;
            float fb1 = (k0 + 1 < VV) ? q1[k0 + 1] : 0.f;
            unsigned ha0 = bf16_rne(fa0), ha1 = bf16_rne(fa1);
            unsigned hb0 = bf16_rne(fb0), hb1 = bf16_rne(fb1);
            HA.u[p] = ha0 | (ha1 << 16);
            HB.u[p] = hb0 | (hb1 << 16);
            LA.u[p] = bf16_rne(fa0 - bfbits2f(ha0)) | (bf16_rne(fa1 - bfbits2f(ha1)) << 16);
            LB.u[p] = bf16_rne(fb0 - bfbits2f(hb0)) | (bf16_rne(fb1 - bfbits2f(hb1)) << 16);
        }
        wxhiA = HA.s; wxloA = LA.s; wxhiB = HB.s; wxloB = LB.s;
    }

    f32x4 bias0v, bias1v;                  // MFMA C-in of the a-chains
    #pragma unroll
    for (int q = 0; q < 4; ++q) {
        int ra = 16 * (2 * w)     + 4 * g + q;
        int rb = 16 * (2 * w + 1) + 4 * g + q;
        bias0v[q] = be_ih[ra] + be_hh[ra];
        bias1v[q] = be_ih[rb] + be_hh[rb];
    }

    // ---------------- x staging / conversion ----------------
    const int c0 = tid >> 4;               // converter: batch row
    const int t0 = tid & 15;               // converter: step within chunk
    const float* xrowc = x + (size_t)(b0 + c0) * SS * VV;
    float xv[VV];

#define XLOAD(CHUNK) {                                                          \
        const float* p_ = xrowc + (size_t)((CHUNK) * CH + t0) * VV;             \
        _Pragma("unroll")                                                       \
        for (int j = 0; j < VV; ++j) xv[j] = p_[j]; }

#define XCONVERT(CB) {                                                          \
        unsigned hb[VV + 1], lb[VV + 1];                                        \
        _Pragma("unroll")                                                       \
        for (int j = 0; j < VV; ++j) {                                          \
            unsigned h_ = bf16_rne(xv[j]);                                      \
            hb[j] = h_; lb[j] = bf16_rne(xv[j] - bfbits2f(h_));                 \
        }                                                                       \
        hb[VV] = 0u; lb[VV] = 0u;                                               \
        _Pragma("unroll")                                                       \
        for (int m = 0; m < 15; ++m) {                                          \
            int g_ = m >> 2, w_ = m & 3;                                        \
            ((unsigned*)&shXhi[CB][t0][g_][c0])[w_] = hb[2*m] | (hb[2*m+1] << 16); \
            ((unsigned*)&shXlo[CB][t0][g_][c0])[w_] = lb[2*m] | (lb[2*m+1] << 16); \
        }                                                                       \
        ((unsigned*)&shXhi[CB][t0][3][c0])[3] = 0u;   /* k=30,31 pad */         \
        ((unsigned*)&shXlo[CB][t0][3][c0])[3] = 0u; }

    {   // zero h buffers (h0 = 0); 512 uint4 total
        uint4 z = make_uint4(0u, 0u, 0u, 0u);
        ((uint4*)shHhi)[tid] = z; ((uint4*)shHhi)[tid + 256] = z;
        ((uint4*)shHlo)[tid] = z; ((uint4*)shHlo)[tid + 256] = z;
    }
    XLOAD(0);
    __syncthreads();
    XCONVERT(0);
    XLOAD(1);
    BLOCK_SYNC;

    // ---------------- encoder step ----------------
#define ENC_STEP(CUR, NXT, SLOC, CB)                                            \
    {                                                                           \
        bf16x8 Bh0 = as_bf16x8(shHhi[CUR][0][g][c]);                            \
        bf16x8 Bh1 = as_bf16x8(shHhi[CUR][1][g][c]);                            \
        bf16x8 Bh2 = as_bf16x8(shHhi[CUR][2][g][c]);                            \
        bf16x8 Bh3 = as_bf16x8(shHhi[CUR][3][g][c]);                            \
        bf16x8 Bl0 = as_bf16x8(shHlo[CUR][0][g][c]);                            \
        bf16x8 Bl1 = as_bf16x8(shHlo[CUR][1][g][c]);                            \
        bf16x8 Bl2 = as_bf16x8(shHlo[CUR][2][g][c]);                            \
        bf16x8 Bl3 = as_bf16x8(shHlo[CUR][3][g][c]);                            \
        bf16x8 Bx  = as_bf16x8(shXhi[CB][SLOC][g][c]);                          \
        bf16x8 Bxl = as_bf16x8(shXlo[CB][SLOC][g][c]);                          \
        f32x4 d0a = bias0v, d1a = bias1v;                                       \
        f32x4 d0b = {0.f,0.f,0.f,0.f}, d1b = {0.f,0.f,0.f,0.f};                 \
        f32x4 d0c = {0.f,0.f,0.f,0.f}, d1c = {0.f,0.f,0.f,0.f};                 \
        d0a = MF(whiA[0], Bh0, d0a);  d1a = MF(whiB[0], Bh0, d1a);              \
        d0b = MF(wloA[0], Bh0, d0b);  d1b = MF(wloB[0], Bh0, d1b);              \
        d0c = MF(whiA[0], Bl0, d0c);  d1c = MF(whiB[0], Bl0, d1c);              \
        d0a = MF(whiA[1], Bh1, d0a);  d1a = MF(whiB[1], Bh1, d1a);              \
        d0b = MF(wloA[1], Bh1, d0b);  d1b = MF(wloB[1], Bh1, d1b);              \
        d0c = MF(whiA[1], Bl1, d0c);  d1c = MF(whiB[1], Bl1, d1c);              \
        d0a = MF(whiA[2], Bh2, d0a);  d1a = MF(whiB[2], Bh2, d1a);              \
        d0b = MF(wloA[2], Bh2, d0b);  d1b = MF(wloB[2], Bh2, d1b);              \
        d0c = MF(whiA[2], Bl2, d0c);  d1c = MF(whiB[2], Bl2, d1c);              \
        d0a = MF(whiA[3], Bh3, d0a);  d1a = MF(whiB[3], Bh3, d1a);              \
        d0b = MF(wloA[3], Bh3, d0b);  d1b = MF(wloB[3], Bh3, d1b);              \
        d0c = MF(whiA[3], Bl3, d0c);  d1c = MF(whiB[3], Bl3, d1c);              \
        d0a = MF(wxhiA, Bx, d0a);     d1a = MF(wxhiB, Bx, d1a);                 \
        d0b = MF(wxloA, Bx, d0b);     d1b = MF(wxloB, Bx, d1b);                 \
        d0c = MF(wxhiA, Bxl, d0c);    d1c = MF(wxhiB, Bxl, d1c);                \
        float hn00 = fast_tanh(d0a[0] + d0b[0] + d0c[0]);                       \
        float hn01 = fast_tanh(d0a[1] + d0b[1] + d0c[1]);                       \
        float hn02 = fast_tanh(d0a[2] + d0b[2] + d0c[2]);                       \
        float hn03 = fast_tanh(d0a[3] + d0b[3] + d0c[3]);                       \
        float hn10 = fast_tanh(d1a[0] + d1b[0] + d1c[0]);                       \
        float hn11 = fast_tanh(d1a[1] + d1b[1] + d1c[1]);                       \
        float hn12 = fast_tanh(d1a[2] + d1b[2] + d1c[2]);                       \
        float hn13 = fast_tanh(d1a[3] + d1b[3] + d1c[3]);                       \
        unsigned h00 = bf16_rne(hn00), h01 = bf16_rne(hn01);                    \
        unsigned h02 = bf16_rne(hn02), h03 = bf16_rne(hn03);                    \
        unsigned h10 = bf16_rne(hn10), h11 = bf16_rne(hn11);                    \
        unsigned h12 = bf16_rne(hn12), h13 = bf16_rne(hn13);                    \
        unsigned l00 = bf16_rne(hn00 - bfbits2f(h00));                          \
        unsigned l01 = bf16_rne(hn01 - bfbits2f(h01));                          \
        unsigned l02 = bf16_rne(hn02 - bfbits2f(h02));                          \
        unsigned l03 = bf16_rne(hn03 - bfbits2f(h03));                          \
        unsigned l10 = bf16_rne(hn10 - bfbits2f(h10));                          \
        unsigned l11 = bf16_rne(hn11 - bfbits2f(h11));                          \
        unsigned l12 = bf16_rne(hn12 - bfbits2f(h12));                          \
        unsigned l13 = bf16_rne(hn13 - bfbits2f(h13));                          \
        { /* tile T0 = 2w: gB = g>>1 */                                         \
            ((uint2*)&shHhi[NXT][w][(g >> 1)][c])[g & 1] =                      \
                make_uint2(h00 | (h01 << 16), h02 | (h03 << 16));               \
            ((uint2*)&shHlo[NXT][w][(g >> 1)][c])[g & 1] =                      \
                make_uint2(l00 | (l01 << 16), l02 | (l03 << 16));               \
        }                                                                       \
        { /* tile T1 = 2w+1: gB = 2 + (g>>1) */                                 \
            ((uint2*)&shHhi[NXT][w][2 + (g >> 1)][c])[g & 1] =                  \
                make_uint2(h10 | (h11 << 16), h12 | (h13 << 16));               \
            ((uint2*)&shHlo[NXT][w][2 + (g >> 1)][c])[g & 1] =                  \
                make_uint2(l10 | (l11 << 16), l12 | (l13 << 16));               \
        }                                                                       \
        BLOCK_SYNC;                                                             \
    }

    int cur = 0;
    for (int tc = 0; tc < SS; tc += CH) {
        const int cb = (tc >> 4) & 1;
        for (int s = 0; s < CH; ++s) {
            ENC_STEP(cur, cur ^ 1, s, cb)
            cur ^= 1;
        }
        if (tc + CH < SS) {
            XCONVERT(cb ^ 1);              // xv holds chunk (tc/CH)+1
            if (tc + 2 * CH < SS) XLOAD((tc >> 4) + 2);
            BLOCK_SYNC;
        }
    }
    // 2048 steps (even) -> final h in buffer 0

    // ---------------- decoder ----------------
    {   // unpack final h: thread -> (row = tid&15, 8 elems)
        int rr = tid & 15;
        int eb = tid >> 4;
        #pragma unroll
        for (int j = 0; j < 8; ++j) {
            int e = eb * 8 + j;
            unsigned wh = ((const unsigned*)&shHhi[0][e >> 5][(e >> 3) & 3][rr])[(e & 7) >> 1];
            unsigned wl = ((const unsigned*)&shHlo[0][e >> 5][(e >> 3) & 3][rr])[(e & 7) >> 1];
            unsigned hh = (e & 1) ? (wh >> 16) : (wh & 0xffffu);
            unsigned ll = (e & 1) ? (wl >> 16) : (wl & 0xffffu);
            hdec[rr][e] = bfbits2f(hh) + bfbits2f(ll);
        }
    }
    __syncthreads();

    // 2 rows per wave (halves), 2 passes -> 16 rows. No barriers below.
    const int hf  = l >> 5;
    const int rl0 = l & 31;
    const int rl  = (rl0 < VV) ? rl0 : (VV - 1);   // lanes >=29 mirror row 28

    for (int pass = 0; pass < 2; ++pass) {
        const int row = 8 * pass + 2 * w + hf;     // 0..15
        float di = bd_ih[rl] + bd_hh[rl];
        {
            const float* wdi = Wd_ih + rl * HH;
            const float* hv  = hdec[row];
            float d0 = 0.f, d1 = 0.f, d2 = 0.f, d3 = 0.f;
            #pragma unroll
            for (int j = 0; j < HH; j += 4) {
                d0 += wdi[j + 0] * hv[j + 0];
                d1 += wdi[j + 1] * hv[j + 1];
                d2 += wdi[j + 2] * hv[j + 2];
                d3 += wdi[j + 3] * hv[j + 3];
            }
            di += (d0 + d1) + (d2 + d3);
        }
        float wd[VV];
        {
            const float* wdr = Wd_hh + rl * VV;
            #pragma unroll
            for (int j = 0; j < VV; ++j) wd[j] = wdr[j];
        }

        float hd = 0.0f;
        float* ob = out + (size_t)(b0 + row) * SS * VV;
        int t = 0;
        for (; t < SS; ++t) {
            float a0 = di, a1 = 0.f, a2 = 0.f, a3 = 0.f;
            #pragma unroll
            for (int j = 0; j < VV; j += 4) {
                a0 += wd[j] * __shfl(hd, j, 32);
                if (j + 1 < VV) a1 += wd[j + 1] * __shfl(hd, j + 1, 32);
                if (j + 2 < VV) a2 += wd[j + 2] * __shfl(hd, j + 2, 32);
                if (j + 3 < VV) a3 += wd[j + 3] * __shfl(hd, j + 3, 32);
            }
            float hn = fast_tanh((a0 + a1) + (a2 + a3));
            int conv = (fabsf(hn - hd) < 1e-6f) ? 1 : 0;
            hd = hn;
            if (rl0 < VV) ob[(size_t)t * VV + rl0] = hn;
            if (__all(conv)) { ++t; break; }
        }

        if (t < SS) {                               // fixed-point bulk fill
            while (t & 3) {                         // align flat offset to 16B
                if (rl0 < VV) ob[(size_t)t * VV + rl0] = hd;
                ++t;
            }
            if (t < SS) {
                // 58 lanes x float4 = 232/sweep; 232%29==0 && 232%4==0 -> exact
                const int phi = (4 * l) % VV;
                #pragma unroll
                for (int h2 = 0; h2 < 2; ++h2) {
                    float* obr = out + (size_t)(b0 + 8 * pass + 2 * w + h2) * SS * VV;
                    float4 v4;
                    v4.x = __shfl(hd, 32 * h2 + phi,              64);
                    v4.y = __shfl(hd, 32 * h2 + (phi + 1) % VV,   64);
                    v4.z = __shfl(hd, 32 * h2 + (phi + 2) % VV,   64);
                    v4.w = __shfl(hd, 32 * h2 + (phi + 3) % VV,   64);
                    if (l < 58) {
                        const long fend = (long)SS * VV;
                        for (long f = (long)t * VV + 4 * l; f + 4 <= fend; f += 232) {
                            *reinterpret_cast<float4*>(obr + f) = v4;
                        }
                    }
                }
            }
        }
    }
}

extern "C" void kernel_launch(void* const* d_in, const int* in_sizes, int n_in,
                              void* d_out, int out_size, void* d_ws, size_t ws_size,
                              hipStream_t stream) {
    const float* x     = (const float*)d_in[0];
    const float* We_ih = (const float*)d_in[1];
    const float* We_hh = (const float*)d_in[2];
    const float* be_ih = (const float*)d_in[3];
    const float* be_hh = (const float*)d_in[4];
    const float* Wd_ih = (const float*)d_in[5];
    const float* Wd_hh = (const float*)d_in[6];
    const float* bd_ih = (const float*)d_in[7];
    const float* bd_hh = (const float*)d_in[8];
    float* out = (float*)d_out;

    rnn_fused<<<dim3(NBLK), dim3(256), 0, stream>>>(
        x, We_ih, We_hh, be_ih, be_hh, Wd_ih, Wd_hh, bd_ih, bd_hh, out);
}